// Round 3
// baseline (329.208 us; speedup 1.0000x reference)
//
#include <hip/hip_runtime.h>
#include <math.h>

#define NN 50000
#define EE 640000
#define IND 23
#define HID 128
#define MIDD 64
#define NCLS 12
#define NB 49          // ceil(NN / 1024) scan chunks
#define QS 32766.0f
#define INVQS (1.0f / 32766.0f)

typedef short short8v __attribute__((ext_vector_type(8)));
typedef float f32x4 __attribute__((ext_vector_type(4)));

// bf16 helpers (RNE), bit-exact and header-free
__device__ __forceinline__ short f2bf(float f) {
    unsigned u = __float_as_uint(f);
    unsigned r = (u + 0x7FFFu + ((u >> 16) & 1u)) >> 16;
    return (short)r;
}
__device__ __forceinline__ float bf2f(short s) {
    return __uint_as_float(((unsigned)(unsigned short)s) << 16);
}

// ---- fused pre-pass: edge count + head-collapse + weight split -------------
// blocks [0,2500): count   [2500,2506): Wcc=Wc1@Wc2   [2506,2634): W2/W3 split
__global__ __launch_bounds__(256) void k_pre(const int* __restrict__ dst,
                                             int* __restrict__ cnt,
                                             const float* __restrict__ Wc1,
                                             const float* __restrict__ bc1,
                                             const float* __restrict__ Wc2,
                                             const float* __restrict__ bc2,
                                             float* __restrict__ Wcc,
                                             float* __restrict__ bcc,
                                             const float* __restrict__ W2,
                                             const float* __restrict__ W3,
                                             short* __restrict__ w2hi,
                                             short* __restrict__ w2lo,
                                             short* __restrict__ w3hi,
                                             short* __restrict__ w3lo) {
    const int bid = blockIdx.x;
    const int tid = threadIdx.x;
    if (bid < 2500) {                       // edge count
        int i = bid * 256 + tid;
        if (i < EE) atomicAdd(&cnt[dst[i]], 1);
        return;
    }
    if (bid < 2506) {                       // collapsed head: Wcc, bcc
        int t = (bid - 2500) * 256 + tid;
        if (t < HID * NCLS) {
            int k = t / NCLS, c = t % NCLS;
            float s = 0.f;
#pragma unroll 8
            for (int j = 0; j < MIDD; ++j) s += Wc1[k * MIDD + j] * Wc2[j * NCLS + c];
            Wcc[t] = s;
        }
        if (t < NCLS) {
            float s = bc2[t];
#pragma unroll 8
            for (int j = 0; j < MIDD; ++j) s += bc1[j] * Wc2[j * NCLS + t];
            bcc[t] = s;
        }
        return;
    }
    // split W (128x128 fp32, k-major) into hi/lo bf16 MFMA B-fragment tables.
    // idx = ((t*4+g)*128 + col)*8 + j  <=>  W[t*32+g*8+j][col]
    int bb = bid - 2506;                    // 0..127
    const float* W = (bb < 64) ? W2 : W3;
    short* hi = (bb < 64) ? w2hi : w3hi;
    short* lo = (bb < 64) ? w2lo : w3lo;
    int i = (bb & 63) * 256 + tid;          // 0..16383
    int k = i >> 7, c = i & 127;
    float w = W[i];
    short h = f2bf(w);
    short l = f2bf(w - bf2f(h));
    int t = k >> 5, g = (k >> 3) & 3, j = k & 7;
    hi[((t * 4 + g) * 128 + c) * 8 + j] = h;
    lo[((t * 4 + g) * 128 + c) * 8 + j] = l;
}

__global__ __launch_bounds__(256) void k_scan_local(const int* __restrict__ cnt,
                                                    int* __restrict__ row_ptr,
                                                    float* __restrict__ dinv,
                                                    int* __restrict__ sums) {
    __shared__ int wtot[4];
    const int tid = threadIdx.x;
    const int wid = tid >> 6, lane = tid & 63;
    const int base = blockIdx.x * 1024 + tid * 4;
    int v[4];
#pragma unroll
    for (int t = 0; t < 4; ++t) {
        int i = base + t;
        v[t] = (i < NN) ? cnt[i] : 0;
        if (i < NN) dinv[i] = rsqrtf((float)v[t] + 1.0f);  // +1 self loop
    }
    int slocal = v[0] + v[1] + v[2] + v[3];
    int val = slocal;
#pragma unroll
    for (int off = 1; off < 64; off <<= 1) {
        int t = __shfl_up(val, off, 64);
        if (lane >= off) val += t;
    }
    if (lane == 63) wtot[wid] = val;
    __syncthreads();
    int woff = 0;
#pragma unroll
    for (int w = 0; w < 4; ++w) woff += (w < wid) ? wtot[w] : 0;
    int run = woff + val - slocal;
#pragma unroll
    for (int t = 0; t < 4; ++t) {
        int i = base + t;
        if (i < NN) row_ptr[i] = run;
        run += v[t];
    }
    if (tid == 255) sums[blockIdx.x] = woff + val;
}

// scan finalize; each block redundantly reduces the 49 partial sums (cheap),
// deleting the separate k_scan_sums launch
__global__ __launch_bounds__(256) void k_scan_apply2(int* __restrict__ row_ptr,
                                                     const int* __restrict__ sums,
                                                     int* __restrict__ cursor) {
    __shared__ int so;
    const int tid = threadIdx.x;
    if (tid < 64) {
        int a = (tid < (int)blockIdx.x) ? sums[tid] : 0;   // exclusive prefix
        int b = (tid < NB) ? sums[tid] : 0;                // grand total
#pragma unroll
        for (int off = 32; off; off >>= 1) {
            a += __shfl_down(a, off, 64);
            b += __shfl_down(b, off, 64);
        }
        if (tid == 0) {
            so = a;
            if (blockIdx.x == NB - 1) row_ptr[NN] = b;
        }
    }
    __syncthreads();
    const int o = so;
    const int base = blockIdx.x * 1024 + tid * 4;
#pragma unroll
    for (int t = 0; t < 4; ++t) {
        int i = base + t;
        if (i < NN) {
            int rp = row_ptr[i] + o;
            row_ptr[i] = rp;
            cursor[i] = rp;
        }
    }
}

// ---- fused fill + pad ------------------------------------------------------
// blocks [0,2500): CSR fill {src, dinv[src]}   [2500,8750): pad x -> xp
__global__ __launch_bounds__(256) void k_fillpad(const int* __restrict__ src,
                                                 const int* __restrict__ dst,
                                                 int* __restrict__ cursor,
                                                 const float* __restrict__ dinv,
                                                 int2* __restrict__ e_sn,
                                                 const float* __restrict__ x,
                                                 float* __restrict__ xp) {
    const int bid = blockIdx.x;
    const int tid = threadIdx.x;
    if (bid < 2500) {
        int i = bid * 256 + tid;
        if (i < EE) {
            int s = src[i];
            int d = dst[i];
            float w = dinv[s];
            int pos = atomicAdd(&cursor[d], 1);
            e_sn[pos] = make_int2(s, __float_as_int(w));
        }
        return;
    }
    int i = (bid - 2500) * 256 + tid;       // over NN*32
    int node = i >> 5, f = i & 31;
    xp[i] = (f < IND) ? x[node * IND + f] * dinv[node] : 0.f;
}

// ---- layer 1 fused: q1 = quant( tanh( (A @ x) @ W1 + b1 ) ) ---------------
__global__ __launch_bounds__(256) void k_l1(const float* __restrict__ xp,
                                            const float* __restrict__ W1,
                                            const float* __restrict__ b1,
                                            const int* __restrict__ row_ptr,
                                            const int2* __restrict__ e_sn,
                                            const float* __restrict__ dinv,
                                            short* __restrict__ outq) {
    const int tid = threadIdx.x;
    const int i = blockIdx.x * 4 + (tid >> 6);
    const int lane = tid & 63;
    const int slot = lane >> 3;     // 8 edge slots
    const int f = lane & 7;         // float4 index within 32-float row
    const float4* xp4 = (const float4*)xp;
    const int beg = row_ptr[i];
    const int deg = row_ptr[i + 1] - beg;
    float4 acc = make_float4(0.f, 0.f, 0.f, 0.f);
    for (int base = 0; base < deg; base += 64) {
        const int cnt = min(64, deg - base);
        int s_l = 0;
        if (lane < cnt) s_l = e_sn[beg + base + lane].x;
        int e = 0;
        for (; e + 8 <= cnt; e += 8) {
            int s = __shfl(s_l, e + slot, 64);
            float4 v = xp4[s * 8 + f];
            acc.x += v.x; acc.y += v.y; acc.z += v.z; acc.w += v.w;
        }
        if (e < cnt) {                          // wave-uniform shfl
            int s = __shfl(s_l, e + slot, 64);
            if (e + slot < cnt) {
                float4 v = xp4[s * 8 + f];
                acc.x += v.x; acc.y += v.y; acc.z += v.z; acc.w += v.w;
            }
        }
    }
#pragma unroll
    for (int off = 32; off >= 8; off >>= 1) {
        acc.x += __shfl_down(acc.x, off, 64);
        acc.y += __shfl_down(acc.y, off, 64);
        acc.z += __shfl_down(acc.z, off, 64);
        acc.w += __shfl_down(acc.w, off, 64);
    }
    const float di = dinv[i];
    if (lane < 8) {
        float4 v = xp4[i * 8 + lane];   // self row (pre-folded)
        acc.x = (acc.x + v.x) * di; acc.y = (acc.y + v.y) * di;
        acc.z = (acc.z + v.z) * di; acc.w = (acc.w + v.w) * di;
    }
    float a0 = b1[lane], a1 = b1[lane + 64];
#pragma unroll
    for (int k = 0; k < IND; ++k) {
        float comp = ((k & 3) == 0) ? acc.x : ((k & 3) == 1) ? acc.y
                   : ((k & 3) == 2) ? acc.z : acc.w;
        float xk = __shfl(comp, k >> 2, 64);
        a0 += xk * W1[k * HID + lane];
        a1 += xk * W1[k * HID + lane + 64];
    }
    outq[i * HID + lane]      = (short)__float2int_rn(tanhf(a0) * QS);
    outq[i * HID + lane + 64] = (short)__float2int_rn(tanhf(a1) * QS);
}

// ---- fused layer: agg(int16 rows) -> split-bf16 MFMA GEMM -> tanh ----------
// Block = 512 thr = 8 waves = 16 nodes. Agg: 2 nodes/wave (wave-per-node inner
// structure kept); lanes 0-15 hold fp32 chunks [8f,8f+8) -> split bf16 hi/lo
// -> LDS chunk slots (17-slot row pad). GEMM: wave w computes cols w*16..+15,
// 12 mfma_f32_16x16x32_bf16 (Ahi@Whi + Ahi@Wlo + Alo@Whi).
// A-frag: lane l = row (l&15), chunk t*4+(l>>4). D: row 4*(l>>4)+r, col l&15.
__device__ __forceinline__ void agg_to_lds(const short8v* __restrict__ h8,
                                           const int* __restrict__ row_ptr,
                                           const int2* __restrict__ e_sn,
                                           const float* __restrict__ dinv,
                                           int nb, int wv, int lane,
                                           short8v* hiS, short8v* loS) {
    const int slot = lane >> 4;
    for (int jn = 0; jn < 2; ++jn) {
        const int r = wv * 2 + jn;
        const int i = nb + r;
        const int beg = row_ptr[i];
        const int deg = row_ptr[i + 1] - beg;
        float facc[8];
#pragma unroll
        for (int t = 0; t < 8; ++t) facc[t] = 0.f;
        for (int base = 0; base < deg; base += 64) {
            const int cnt = min(64, deg - base);
            int s_l = 0; float n_l = 0.f;
            if (lane < cnt) {
                int2 sn = e_sn[beg + base + lane];
                s_l = sn.x;
                n_l = __int_as_float(sn.y);
            }
            int e = 0;
#pragma unroll 4
            for (; e + 4 <= cnt; e += 4) {
                int s = __shfl(s_l, e + slot, 64);
                float nr = __shfl(n_l, e + slot, 64);
                short8v v = h8[s * 16 + (lane & 15)];
#pragma unroll
                for (int t = 0; t < 8; ++t) facc[t] += (float)v[t] * nr;
            }
            if (e < cnt) {                      // wave-uniform shfl
                int s = __shfl(s_l, e + slot, 64);
                float nr = __shfl(n_l, e + slot, 64);
                if (e + slot < cnt) {
                    short8v v = h8[s * 16 + (lane & 15)];
#pragma unroll
                    for (int t = 0; t < 8; ++t) facc[t] += (float)v[t] * nr;
                }
            }
        }
#pragma unroll
        for (int off = 32; off >= 16; off >>= 1)
#pragma unroll
            for (int t = 0; t < 8; ++t) facc[t] += __shfl_down(facc[t], off, 64);
        if (lane < 16) {
            const float di = dinv[i];
            const float sc = di * INVQS;
            short8v v = h8[i * 16 + lane];      // self row
            short8v hi8, lo8;
#pragma unroll
            for (int t = 0; t < 8; ++t) {
                float o = (facc[t] + di * (float)v[t]) * sc;
                short h = f2bf(o);
                hi8[t] = h;
                lo8[t] = f2bf(o - bf2f(h));
            }
            hiS[r * 17 + lane] = hi8;
            loS[r * 17 + lane] = lo8;
        }
    }
}

// layer 2: q2 = quant(tanh(agg(q1) @ W2 + b2))  (q2 is a distinct buffer —
// in-kernel read/write alias of q would race across blocks)
__global__ __launch_bounds__(512) void k_layer_q(const short* __restrict__ hq,
                                                 const int* __restrict__ row_ptr,
                                                 const int2* __restrict__ e_sn,
                                                 const float* __restrict__ dinv,
                                                 const short* __restrict__ whi,
                                                 const short* __restrict__ wlo,
                                                 const float* __restrict__ bias,
                                                 short* __restrict__ qout) {
    __shared__ short8v hiS[16 * 17];
    __shared__ short8v loS[16 * 17];
    __shared__ short8v q2v[16 * 17];
    const int tid = threadIdx.x;
    const int wv = tid >> 6, lane = tid & 63;
    const int nb = blockIdx.x * 16;
    const short8v* h8 = (const short8v*)hq;
    agg_to_lds(h8, row_ptr, e_sn, dinv, nb, wv, lane, hiS, loS);
    __syncthreads();
    const int g = lane >> 4, c16 = lane & 15;
    const short8v* whi8 = (const short8v*)whi;
    const short8v* wlo8 = (const short8v*)wlo;
    f32x4 acc = f32x4{0.f, 0.f, 0.f, 0.f};
#pragma unroll
    for (int t = 0; t < 4; ++t) {
        short8v ah = hiS[c16 * 17 + t * 4 + g];
        short8v al = loS[c16 * 17 + t * 4 + g];
        const int wb = (t * 4 + g) * 128 + wv * 16 + c16;
        short8v bh = whi8[wb];
        short8v bl = wlo8[wb];
        acc = __builtin_amdgcn_mfma_f32_16x16x32_bf16(ah, bh, acc, 0, 0, 0);
        acc = __builtin_amdgcn_mfma_f32_16x16x32_bf16(ah, bl, acc, 0, 0, 0);
        acc = __builtin_amdgcn_mfma_f32_16x16x32_bf16(al, bh, acc, 0, 0, 0);
    }
    const float bb = bias[wv * 16 + c16];
    short* q2s = (short*)q2v;
#pragma unroll
    for (int r2 = 0; r2 < 4; ++r2) {
        float v = tanhf(acc[r2] + bb);
        q2s[(4 * g + r2) * 136 + wv * 16 + c16] = (short)__float2int_rn(v * QS);
    }
    __syncthreads();
    if (tid < 256) {                 // coalesced 16B row stores
        int row = tid >> 4, seg = tid & 15;
        ((short8v*)qout)[(nb + row) * 16 + seg] = q2v[row * 17 + seg];
    }
}

// layer 3 + head: out = tanh(agg(q2) @ W3 + b3) @ Wcc + bcc (h3 stays on-chip)
__global__ __launch_bounds__(512) void k_layer_head(const short* __restrict__ hq,
                                                    const int* __restrict__ row_ptr,
                                                    const int2* __restrict__ e_sn,
                                                    const float* __restrict__ dinv,
                                                    const short* __restrict__ whi,
                                                    const short* __restrict__ wlo,
                                                    const float* __restrict__ bias,
                                                    const float* __restrict__ Wcc,
                                                    const float* __restrict__ bcc,
                                                    float* __restrict__ outp) {
    __shared__ short8v hiS[16 * 17];
    __shared__ short8v loS[16 * 17];
    __shared__ float WccS[HID * NCLS];
    __shared__ float bccS[NCLS];
    __shared__ float psum[8][16][NCLS];
    const int tid = threadIdx.x;
    const int wv = tid >> 6, lane = tid & 63;
    const int nb = blockIdx.x * 16;
    const short8v* h8 = (const short8v*)hq;
    for (int t = tid; t < HID * NCLS; t += 512) WccS[t] = Wcc[t];
    if (tid < NCLS) bccS[tid] = bcc[tid];
    agg_to_lds(h8, row_ptr, e_sn, dinv, nb, wv, lane, hiS, loS);
    __syncthreads();
    const int g = lane >> 4, c16 = lane & 15;
    const short8v* whi8 = (const short8v*)whi;
    const short8v* wlo8 = (const short8v*)wlo;
    f32x4 acc = f32x4{0.f, 0.f, 0.f, 0.f};
#pragma unroll
    for (int t = 0; t < 4; ++t) {
        short8v ah = hiS[c16 * 17 + t * 4 + g];
        short8v al = loS[c16 * 17 + t * 4 + g];
        const int wb = (t * 4 + g) * 128 + wv * 16 + c16;
        short8v bh = whi8[wb];
        short8v bl = wlo8[wb];
        acc = __builtin_amdgcn_mfma_f32_16x16x32_bf16(ah, bh, acc, 0, 0, 0);
        acc = __builtin_amdgcn_mfma_f32_16x16x32_bf16(ah, bl, acc, 0, 0, 0);
        acc = __builtin_amdgcn_mfma_f32_16x16x32_bf16(al, bh, acc, 0, 0, 0);
    }
    const float bb = bias[wv * 16 + c16];
    float part[4][NCLS];
#pragma unroll
    for (int r2 = 0; r2 < 4; ++r2)
#pragma unroll
        for (int c = 0; c < NCLS; ++c) part[r2][c] = 0.f;
    const float4* wr = (const float4*)&WccS[(wv * 16 + c16) * NCLS];
    float4 wa = wr[0], wb2 = wr[1], wc = wr[2];
#pragma unroll
    for (int r2 = 0; r2 < 4; ++r2) {
        float v = tanhf(acc[r2] + bb);
        part[r2][0]  += v * wa.x;  part[r2][1]  += v * wa.y;
        part[r2][2]  += v * wa.z;  part[r2][3]  += v * wa.w;
        part[r2][4]  += v * wb2.x; part[r2][5]  += v * wb2.y;
        part[r2][6]  += v * wb2.z; part[r2][7]  += v * wb2.w;
        part[r2][8]  += v * wc.x;  part[r2][9]  += v * wc.y;
        part[r2][10] += v * wc.z;  part[r2][11] += v * wc.w;
    }
#pragma unroll
    for (int off = 8; off; off >>= 1)
#pragma unroll
        for (int r2 = 0; r2 < 4; ++r2)
#pragma unroll
            for (int c = 0; c < NCLS; ++c)
                part[r2][c] += __shfl_down(part[r2][c], off, 64);
    if (c16 == 0) {
#pragma unroll
        for (int r2 = 0; r2 < 4; ++r2)
#pragma unroll
            for (int c = 0; c < NCLS; ++c)
                psum[wv][4 * g + r2][c] = part[r2][c];
    }
    __syncthreads();
    if (tid < 16 * NCLS) {
        int row = tid / NCLS, c = tid % NCLS;
        float s = bccS[c];
#pragma unroll
        for (int w = 0; w < 8; ++w) s += psum[w][row][c];
        outp[(nb + row) * NCLS + c] = s;
    }
}

// ---- launch ---------------------------------------------------------------

extern "C" void kernel_launch(void* const* d_in, const int* in_sizes, int n_in,
                              void* d_out, int out_size, void* d_ws, size_t ws_size,
                              hipStream_t stream) {
    const float* x    = (const float*)d_in[0];
    const int*   edge = (const int*)d_in[1];
    const int*   src  = edge;
    const int*   dst  = edge + EE;
    const float* W1  = (const float*)d_in[2];  const float* b1  = (const float*)d_in[3];
    const float* W2  = (const float*)d_in[4];  const float* b2  = (const float*)d_in[5];
    const float* W3  = (const float*)d_in[6];  const float* b3  = (const float*)d_in[7];
    const float* Wc1 = (const float*)d_in[8];  const float* bc1 = (const float*)d_in[9];
    const float* Wc2 = (const float*)d_in[10]; const float* bc2 = (const float*)d_in[11];
    float* outp = (float*)d_out;

    char* p = (char*)d_ws;
    int*   cnt     = (int*)p;   p += 200064;          // NN ints, padded
    int*   row_ptr = (int*)p;   p += 200064;          // NN+1 ints, padded
    float* dinv    = (float*)p; p += 200064;
    int*   sums    = (int*)p;   p += 256;
    int2*  e_sn    = (int2*)p;  p += (size_t)EE * 8;  // packed {src, dinv[src]}
    float* xp      = (float*)p; p += (size_t)NN * 32 * 4;    // padded pre-folded x
    short* q1      = (short*)p; p += (size_t)NN * HID * 2;   // int16 tanh layer1
    short* q2      = (short*)p; p += (size_t)NN * HID * 2;   // int16 tanh layer2
    float* Wcc     = (float*)p; p += HID * NCLS * 4;         // collapsed head weight
    float* bcc     = (float*)p; p += 256;                    // collapsed head bias
    short* w2hi    = (short*)p; p += 32768;           // bf16 frag tables (128x128)
    short* w2lo    = (short*)p; p += 32768;
    short* w3hi    = (short*)p; p += 32768;
    short* w3lo    = (short*)p; p += 32768;

    // graph build + weight preprocessing (8 dispatches total incl. memset)
    hipMemsetAsync(cnt, 0, (size_t)NN * 4, stream);
    k_pre        <<<2634, 256, 0, stream>>>(dst, cnt, Wc1, bc1, Wc2, bc2, Wcc, bcc,
                                            W2, W3, w2hi, w2lo, w3hi, w3lo);
    k_scan_local <<<NB, 256, 0, stream>>>(cnt, row_ptr, dinv, sums);
    k_scan_apply2<<<NB, 256, 0, stream>>>(row_ptr, sums, cnt);   // cnt becomes cursor
    k_fillpad    <<<8750, 256, 0, stream>>>(src, dst, cnt, dinv, e_sn, x, xp);

    // layer 1: q1 = quant(tanh((A@x)@W1 + b1))
    k_l1        <<<NN / 4, 256, 0, stream>>>(xp, W1, b1, row_ptr, e_sn, dinv, q1);
    // layer 2 fused: agg(q1) -> mfma gemm -> tanh -> q2
    k_layer_q   <<<NN / 16, 512, 0, stream>>>(q1, row_ptr, e_sn, dinv, w2hi, w2lo, b2, q2);
    // layer 3 fused: agg(q2) -> mfma gemm -> tanh -> head -> out
    k_layer_head<<<NN / 16, 512, 0, stream>>>(q2, row_ptr, e_sn, dinv, w3hi, w3lo, b3,
                                              Wcc, bcc, outp);
}

// Round 4
// 300.453 us; speedup vs baseline: 1.0957x; 1.0957x over previous
//
#include <hip/hip_runtime.h>
#include <math.h>

#define NN 50000
#define EE 640000
#define IND 23
#define HID 128
#define MIDD 64
#define NCLS 12
#define NB 49          // ceil(NN / 1024) scan chunks
#define QS 32766.0f
#define INVQS (1.0f / 32766.0f)

typedef short short8v __attribute__((ext_vector_type(8)));
typedef float f32x4 __attribute__((ext_vector_type(4)));

// bf16 helpers (RNE), bit-exact and header-free
__device__ __forceinline__ short f2bf(float f) {
    unsigned u = __float_as_uint(f);
    unsigned r = (u + 0x7FFFu + ((u >> 16) & 1u)) >> 16;
    return (short)r;
}
__device__ __forceinline__ float bf2f(short s) {
    return __uint_as_float(((unsigned)(unsigned short)s) << 16);
}

// ---- fused pre-pass: edge count + head-collapse + weight split -------------
// blocks [0,2500): count   [2500,2506): Wcc=Wc1@Wc2   [2506,2634): W2/W3 split
__global__ __launch_bounds__(256) void k_pre(const int* __restrict__ dst,
                                             int* __restrict__ cnt,
                                             const float* __restrict__ Wc1,
                                             const float* __restrict__ bc1,
                                             const float* __restrict__ Wc2,
                                             const float* __restrict__ bc2,
                                             float* __restrict__ Wcc,
                                             float* __restrict__ bcc,
                                             const float* __restrict__ W2,
                                             const float* __restrict__ W3,
                                             short* __restrict__ w2hi,
                                             short* __restrict__ w2lo,
                                             short* __restrict__ w3hi,
                                             short* __restrict__ w3lo) {
    const int bid = blockIdx.x;
    const int tid = threadIdx.x;
    if (bid < 2500) {                       // edge count
        int i = bid * 256 + tid;
        if (i < EE) atomicAdd(&cnt[dst[i]], 1);
        return;
    }
    if (bid < 2506) {                       // collapsed head: Wcc, bcc
        int t = (bid - 2500) * 256 + tid;
        if (t < HID * NCLS) {
            int k = t / NCLS, c = t % NCLS;
            float s = 0.f;
#pragma unroll 8
            for (int j = 0; j < MIDD; ++j) s += Wc1[k * MIDD + j] * Wc2[j * NCLS + c];
            Wcc[t] = s;
        }
        if (t < NCLS) {
            float s = bc2[t];
#pragma unroll 8
            for (int j = 0; j < MIDD; ++j) s += bc1[j] * Wc2[j * NCLS + t];
            bcc[t] = s;
        }
        return;
    }
    // split W (128x128 fp32, k-major) into hi/lo bf16 MFMA B-fragment tables.
    // idx = ((t*4+g)*128 + col)*8 + j  <=>  W[t*32+g*8+j][col]
    int bb = bid - 2506;                    // 0..127
    const float* W = (bb < 64) ? W2 : W3;
    short* hi = (bb < 64) ? w2hi : w3hi;
    short* lo = (bb < 64) ? w2lo : w3lo;
    int i = (bb & 63) * 256 + tid;          // 0..16383
    int k = i >> 7, c = i & 127;
    float w = W[i];
    short h = f2bf(w);
    short l = f2bf(w - bf2f(h));
    int t = k >> 5, g = (k >> 3) & 3, j = k & 7;
    hi[((t * 4 + g) * 128 + c) * 8 + j] = h;
    lo[((t * 4 + g) * 128 + c) * 8 + j] = l;
}

__global__ __launch_bounds__(256) void k_scan_local(const int* __restrict__ cnt,
                                                    int* __restrict__ row_ptr,
                                                    float* __restrict__ dinv,
                                                    int* __restrict__ sums) {
    __shared__ int wtot[4];
    const int tid = threadIdx.x;
    const int wid = tid >> 6, lane = tid & 63;
    const int base = blockIdx.x * 1024 + tid * 4;
    int v[4];
#pragma unroll
    for (int t = 0; t < 4; ++t) {
        int i = base + t;
        v[t] = (i < NN) ? cnt[i] : 0;
        if (i < NN) dinv[i] = rsqrtf((float)v[t] + 1.0f);  // +1 self loop
    }
    int slocal = v[0] + v[1] + v[2] + v[3];
    int val = slocal;
#pragma unroll
    for (int off = 1; off < 64; off <<= 1) {
        int t = __shfl_up(val, off, 64);
        if (lane >= off) val += t;
    }
    if (lane == 63) wtot[wid] = val;
    __syncthreads();
    int woff = 0;
#pragma unroll
    for (int w = 0; w < 4; ++w) woff += (w < wid) ? wtot[w] : 0;
    int run = woff + val - slocal;
#pragma unroll
    for (int t = 0; t < 4; ++t) {
        int i = base + t;
        if (i < NN) row_ptr[i] = run;
        run += v[t];
    }
    if (tid == 255) sums[blockIdx.x] = woff + val;
}

// scan finalize; each block redundantly reduces the 49 partial sums (cheap),
// deleting the separate k_scan_sums launch
__global__ __launch_bounds__(256) void k_scan_apply2(int* __restrict__ row_ptr,
                                                     const int* __restrict__ sums,
                                                     int* __restrict__ cursor) {
    __shared__ int so;
    const int tid = threadIdx.x;
    if (tid < 64) {
        int a = (tid < (int)blockIdx.x) ? sums[tid] : 0;   // exclusive prefix
        int b = (tid < NB) ? sums[tid] : 0;                // grand total
#pragma unroll
        for (int off = 32; off; off >>= 1) {
            a += __shfl_down(a, off, 64);
            b += __shfl_down(b, off, 64);
        }
        if (tid == 0) {
            so = a;
            if (blockIdx.x == NB - 1) row_ptr[NN] = b;
        }
    }
    __syncthreads();
    const int o = so;
    const int base = blockIdx.x * 1024 + tid * 4;
#pragma unroll
    for (int t = 0; t < 4; ++t) {
        int i = base + t;
        if (i < NN) {
            int rp = row_ptr[i] + o;
            row_ptr[i] = rp;
            cursor[i] = rp;
        }
    }
}

// ---- fused fill + pad ------------------------------------------------------
// blocks [0,2500): CSR fill {src, dinv[src]}   [2500,8750): pad x -> xp
__global__ __launch_bounds__(256) void k_fillpad(const int* __restrict__ src,
                                                 const int* __restrict__ dst,
                                                 int* __restrict__ cursor,
                                                 const float* __restrict__ dinv,
                                                 int2* __restrict__ e_sn,
                                                 const float* __restrict__ x,
                                                 float* __restrict__ xp) {
    const int bid = blockIdx.x;
    const int tid = threadIdx.x;
    if (bid < 2500) {
        int i = bid * 256 + tid;
        if (i < EE) {
            int s = src[i];
            int d = dst[i];
            float w = dinv[s];
            int pos = atomicAdd(&cursor[d], 1);
            e_sn[pos] = make_int2(s, __float_as_int(w));
        }
        return;
    }
    int i = (bid - 2500) * 256 + tid;       // over NN*32
    int node = i >> 5, f = i & 31;
    xp[i] = (f < IND) ? x[node * IND + f] * dinv[node] : 0.f;
}

// ---- layer 1 fused: q1 = quant( tanh( (A @ x) @ W1 + b1 ) ) ---------------
__global__ __launch_bounds__(256) void k_l1(const float* __restrict__ xp,
                                            const float* __restrict__ W1,
                                            const float* __restrict__ b1,
                                            const int* __restrict__ row_ptr,
                                            const int2* __restrict__ e_sn,
                                            const float* __restrict__ dinv,
                                            short* __restrict__ outq) {
    const int tid = threadIdx.x;
    const int i = blockIdx.x * 4 + (tid >> 6);
    const int lane = tid & 63;
    const int slot = lane >> 3;     // 8 edge slots
    const int f = lane & 7;         // float4 index within 32-float row
    const float4* xp4 = (const float4*)xp;
    const int beg = row_ptr[i];
    const int deg = row_ptr[i + 1] - beg;
    float4 acc = make_float4(0.f, 0.f, 0.f, 0.f);
    for (int base = 0; base < deg; base += 64) {
        const int cnt = min(64, deg - base);
        int s_l = 0;
        if (lane < cnt) s_l = e_sn[beg + base + lane].x;
        int e = 0;
        for (; e + 8 <= cnt; e += 8) {
            int s = __shfl(s_l, e + slot, 64);
            float4 v = xp4[s * 8 + f];
            acc.x += v.x; acc.y += v.y; acc.z += v.z; acc.w += v.w;
        }
        if (e < cnt) {                          // wave-uniform shfl
            int s = __shfl(s_l, e + slot, 64);
            if (e + slot < cnt) {
                float4 v = xp4[s * 8 + f];
                acc.x += v.x; acc.y += v.y; acc.z += v.z; acc.w += v.w;
            }
        }
    }
#pragma unroll
    for (int off = 32; off >= 8; off >>= 1) {
        acc.x += __shfl_down(acc.x, off, 64);
        acc.y += __shfl_down(acc.y, off, 64);
        acc.z += __shfl_down(acc.z, off, 64);
        acc.w += __shfl_down(acc.w, off, 64);
    }
    const float di = dinv[i];
    if (lane < 8) {
        float4 v = xp4[i * 8 + lane];   // self row (pre-folded)
        acc.x = (acc.x + v.x) * di; acc.y = (acc.y + v.y) * di;
        acc.z = (acc.z + v.z) * di; acc.w = (acc.w + v.w) * di;
    }
    float a0 = b1[lane], a1 = b1[lane + 64];
#pragma unroll
    for (int k = 0; k < IND; ++k) {
        float comp = ((k & 3) == 0) ? acc.x : ((k & 3) == 1) ? acc.y
                   : ((k & 3) == 2) ? acc.z : acc.w;
        float xk = __shfl(comp, k >> 2, 64);
        a0 += xk * W1[k * HID + lane];
        a1 += xk * W1[k * HID + lane + 64];
    }
    outq[i * HID + lane]      = (short)__float2int_rn(tanhf(a0) * QS);
    outq[i * HID + lane + 64] = (short)__float2int_rn(tanhf(a1) * QS);
}

// ---- aggregation over int16 tanh rows (lean, barrier-free, wave-per-node) --
// aggf_i = dinv_i * ( sum_s dinv_s*q_s + dinv_i*q_i ) / QS
__global__ __launch_bounds__(256) void k_aggq(const short* __restrict__ hq,
                                              const int* __restrict__ row_ptr,
                                              const int2* __restrict__ e_sn,
                                              const float* __restrict__ dinv,
                                              float* __restrict__ aggf) {
    const int tid = threadIdx.x;
    const int i = blockIdx.x * 4 + (tid >> 6);
    const int lane = tid & 63;
    const int slot = lane >> 4;     // 4 edge slots
    const int f = lane & 15;        // short8 index within 128-short row
    const short8v* h8 = (const short8v*)hq;
    const int beg = row_ptr[i];
    const int deg = row_ptr[i + 1] - beg;
    float facc[8];
#pragma unroll
    for (int t = 0; t < 8; ++t) facc[t] = 0.f;
    for (int base = 0; base < deg; base += 64) {
        const int cnt = min(64, deg - base);
        int s_l = 0; float n_l = 0.f;
        if (lane < cnt) {
            int2 sn = e_sn[beg + base + lane];
            s_l = sn.x;
            n_l = __int_as_float(sn.y);
        }
        int e = 0;
#pragma unroll 4
        for (; e + 4 <= cnt; e += 4) {
            int s = __shfl(s_l, e + slot, 64);
            float nr = __shfl(n_l, e + slot, 64);
            short8v v = h8[s * 16 + f];
#pragma unroll
            for (int t = 0; t < 8; ++t) facc[t] += (float)v[t] * nr;
        }
        if (e < cnt) {                          // wave-uniform shfl
            int s = __shfl(s_l, e + slot, 64);
            float nr = __shfl(n_l, e + slot, 64);
            if (e + slot < cnt) {
                short8v v = h8[s * 16 + f];
#pragma unroll
                for (int t = 0; t < 8; ++t) facc[t] += (float)v[t] * nr;
            }
        }
    }
#pragma unroll
    for (int off = 32; off >= 16; off >>= 1)
#pragma unroll
        for (int t = 0; t < 8; ++t) facc[t] += __shfl_down(facc[t], off, 64);
    if (lane < 16) {
        const float di = dinv[i];
        const float sc = di * INVQS;
        short8v v = h8[i * 16 + lane];          // self row
        float4 o0, o1;
        o0.x = (facc[0] + di * (float)v[0]) * sc;
        o0.y = (facc[1] + di * (float)v[1]) * sc;
        o0.z = (facc[2] + di * (float)v[2]) * sc;
        o0.w = (facc[3] + di * (float)v[3]) * sc;
        o1.x = (facc[4] + di * (float)v[4]) * sc;
        o1.y = (facc[5] + di * (float)v[5]) * sc;
        o1.z = (facc[6] + di * (float)v[6]) * sc;
        o1.w = (facc[7] + di * (float)v[7]) * sc;
        ((float4*)aggf)[i * 32 + lane * 2]     = o0;
        ((float4*)aggf)[i * 32 + lane * 2 + 1] = o1;
    }
}

// ---- MFMA split-bf16 GEMM: C = A @ W via Ahi@Whi + Ahi@Wlo + Alo@Whi ------
// Wave = 16 rows x 128 cols; block = 64 rows. 96 mfma_f32_16x16x32_bf16/wave.
//   A: lane l holds A[l&15][8*(l>>4)+j]   B: lane l holds B[8*(l>>4)+j][l&15]
//   D: lane l holds D[4*(l>>4)+r][l&15]
__device__ __forceinline__ void gemm_core(const float* __restrict__ hin,
                                          const short8v* __restrict__ whi8,
                                          const short8v* __restrict__ wlo8,
                                          int row, bool rv, int g, int c16,
                                          f32x4 acc[8]) {
#pragma unroll
    for (int t = 0; t < 4; ++t) {
        float4 a0 = make_float4(0.f, 0.f, 0.f, 0.f), a1 = a0;
        if (rv) {
            const float4* hp = (const float4*)&hin[row * HID + t * 32 + g * 8];
            a0 = hp[0]; a1 = hp[1];
        }
        float av[8];
        av[0] = a0.x; av[1] = a0.y; av[2] = a0.z; av[3] = a0.w;
        av[4] = a1.x; av[5] = a1.y; av[6] = a1.z; av[7] = a1.w;
        short8v ahi, alo;
#pragma unroll
        for (int j = 0; j < 8; ++j) {
            short h = f2bf(av[j]);
            ahi[j] = h;
            alo[j] = f2bf(av[j] - bf2f(h));
        }
        const int wb = (t * 4 + g) * 128 + c16;
#pragma unroll
        for (int n = 0; n < 8; ++n) {
            short8v bh = whi8[wb + n * 16];
            short8v bl = wlo8[wb + n * 16];
            acc[n] = __builtin_amdgcn_mfma_f32_16x16x32_bf16(ahi, bh, acc[n], 0, 0, 0);
            acc[n] = __builtin_amdgcn_mfma_f32_16x16x32_bf16(ahi, bl, acc[n], 0, 0, 0);
            acc[n] = __builtin_amdgcn_mfma_f32_16x16x32_bf16(alo, bh, acc[n], 0, 0, 0);
        }
    }
}

// layer 2: qout = int16 quant(tanh(A@W + b))
__global__ __launch_bounds__(256) void k_gemm_q(const float* __restrict__ hin,
                                                const short* __restrict__ whi,
                                                const short* __restrict__ wlo,
                                                const float* __restrict__ bias,
                                                short* __restrict__ qout) {
    const int tid = threadIdx.x;
    const int lane = tid & 63, w = tid >> 6;
    const int g = lane >> 4, c16 = lane & 15;
    const int rbase = blockIdx.x * 64 + w * 16;
    f32x4 acc[8];
#pragma unroll
    for (int n = 0; n < 8; ++n) acc[n] = f32x4{0.f, 0.f, 0.f, 0.f};
    gemm_core(hin, (const short8v*)whi, (const short8v*)wlo,
              rbase + c16, (rbase + c16) < NN, g, c16, acc);
#pragma unroll
    for (int n = 0; n < 8; ++n) {
        const float bb = bias[n * 16 + c16];
#pragma unroll
        for (int r = 0; r < 4; ++r) {
            int nd = rbase + 4 * g + r;
            if (nd < NN) {
                float v = tanhf(acc[n][r] + bb);
                qout[nd * HID + n * 16 + c16] = (short)__float2int_rn(v * QS);
            }
        }
    }
}

// layer 3 + fused head: out = tanh(A@W + b) @ Wcc + bcc  (h3 never hits HBM;
// head works directly on the MFMA D-register layout, 16-lane shfl reduce)
__global__ __launch_bounds__(256) void k_gemm_head(const float* __restrict__ hin,
                                                   const short* __restrict__ whi,
                                                   const short* __restrict__ wlo,
                                                   const float* __restrict__ bias,
                                                   const float* __restrict__ Wcc,
                                                   const float* __restrict__ bcc,
                                                   float* __restrict__ outp) {
    __shared__ float WccS[HID * NCLS + 16];
    const int tid = threadIdx.x;
    const int lane = tid & 63, w = tid >> 6;
    const int g = lane >> 4, c16 = lane & 15;
    const int rbase = blockIdx.x * 64 + w * 16;
    for (int t = tid; t < HID * NCLS; t += 256) WccS[t] = Wcc[t];
    if (tid < NCLS) WccS[HID * NCLS + tid] = bcc[tid];
    __syncthreads();
    f32x4 acc[8];
#pragma unroll
    for (int n = 0; n < 8; ++n) acc[n] = f32x4{0.f, 0.f, 0.f, 0.f};
    gemm_core(hin, (const short8v*)whi, (const short8v*)wlo,
              rbase + c16, (rbase + c16) < NN, g, c16, acc);
    float part[4][12];
#pragma unroll
    for (int r = 0; r < 4; ++r)
#pragma unroll
        for (int c = 0; c < 12; ++c) part[r][c] = 0.f;
#pragma unroll
    for (int n = 0; n < 8; ++n) {
        const float bb = bias[n * 16 + c16];
        const float4* wr = (const float4*)&WccS[(n * 16 + c16) * NCLS];
        float4 wa = wr[0], wb = wr[1], wc = wr[2];
#pragma unroll
        for (int r = 0; r < 4; ++r) {
            float v = tanhf(acc[n][r] + bb);
            part[r][0]  += v * wa.x; part[r][1]  += v * wa.y;
            part[r][2]  += v * wa.z; part[r][3]  += v * wa.w;
            part[r][4]  += v * wb.x; part[r][5]  += v * wb.y;
            part[r][6]  += v * wb.z; part[r][7]  += v * wb.w;
            part[r][8]  += v * wc.x; part[r][9]  += v * wc.y;
            part[r][10] += v * wc.z; part[r][11] += v * wc.w;
        }
    }
#pragma unroll
    for (int off = 8; off; off >>= 1)
#pragma unroll
        for (int r = 0; r < 4; ++r)
#pragma unroll
            for (int c = 0; c < 12; ++c)
                part[r][c] += __shfl_down(part[r][c], off, 64);
    if (c16 == 0) {
#pragma unroll
        for (int r = 0; r < 4; ++r) {
            int nd = rbase + 4 * g + r;
            if (nd < NN) {
                float4* op = (float4*)&outp[nd * NCLS];
                op[0] = make_float4(part[r][0] + WccS[HID * NCLS + 0],
                                    part[r][1] + WccS[HID * NCLS + 1],
                                    part[r][2] + WccS[HID * NCLS + 2],
                                    part[r][3] + WccS[HID * NCLS + 3]);
                op[1] = make_float4(part[r][4] + WccS[HID * NCLS + 4],
                                    part[r][5] + WccS[HID * NCLS + 5],
                                    part[r][6] + WccS[HID * NCLS + 6],
                                    part[r][7] + WccS[HID * NCLS + 7]);
                op[2] = make_float4(part[r][8] + WccS[HID * NCLS + 8],
                                    part[r][9] + WccS[HID * NCLS + 9],
                                    part[r][10] + WccS[HID * NCLS + 10],
                                    part[r][11] + WccS[HID * NCLS + 11]);
            }
        }
    }
}

// ---- launch ---------------------------------------------------------------

extern "C" void kernel_launch(void* const* d_in, const int* in_sizes, int n_in,
                              void* d_out, int out_size, void* d_ws, size_t ws_size,
                              hipStream_t stream) {
    const float* x    = (const float*)d_in[0];
    const int*   edge = (const int*)d_in[1];
    const int*   src  = edge;
    const int*   dst  = edge + EE;
    const float* W1  = (const float*)d_in[2];  const float* b1  = (const float*)d_in[3];
    const float* W2  = (const float*)d_in[4];  const float* b2  = (const float*)d_in[5];
    const float* W3  = (const float*)d_in[6];  const float* b3  = (const float*)d_in[7];
    const float* Wc1 = (const float*)d_in[8];  const float* bc1 = (const float*)d_in[9];
    const float* Wc2 = (const float*)d_in[10]; const float* bc2 = (const float*)d_in[11];
    float* outp = (float*)d_out;

    char* p = (char*)d_ws;
    int*   cnt     = (int*)p;   p += 200064;          // NN ints, padded
    int*   row_ptr = (int*)p;   p += 200064;          // NN+1 ints, padded
    float* dinv    = (float*)p; p += 200064;
    int*   sums    = (int*)p;   p += 256;
    int2*  e_sn    = (int2*)p;  p += (size_t)EE * 8;  // packed {src, dinv[src]}
    float* xp      = (float*)p; p += (size_t)NN * 32 * 4;    // padded pre-folded x
    short* q       = (short*)p; p += (size_t)NN * HID * 2;   // int16 tanh (q1/q2 alias)
    float* aggf    = (float*)p; p += (size_t)NN * HID * 4;   // fp32 agg (gemm input)
    float* Wcc     = (float*)p; p += HID * NCLS * 4;         // collapsed head weight
    float* bcc     = (float*)p; p += 256;                    // collapsed head bias
    short* w2hi    = (short*)p; p += 32768;           // bf16 frag tables (128x128)
    short* w2lo    = (short*)p; p += 32768;
    short* w3hi    = (short*)p; p += 32768;
    short* w3lo    = (short*)p; p += 32768;

    // graph build + weight preprocessing (fused front-end, 5 dispatches)
    hipMemsetAsync(cnt, 0, (size_t)NN * 4, stream);
    k_pre        <<<2634, 256, 0, stream>>>(dst, cnt, Wc1, bc1, Wc2, bc2, Wcc, bcc,
                                            W2, W3, w2hi, w2lo, w3hi, w3lo);
    k_scan_local <<<NB, 256, 0, stream>>>(cnt, row_ptr, dinv, sums);
    k_scan_apply2<<<NB, 256, 0, stream>>>(row_ptr, sums, cnt);   // cnt becomes cursor
    k_fillpad    <<<8750, 256, 0, stream>>>(src, dst, cnt, dinv, e_sn, x, xp);

    // layer 1: q1 = quant(tanh((A@x)@W1 + b1))
    k_l1  <<<NN / 4, 256, 0, stream>>>(xp, W1, b1, row_ptr, e_sn, dinv, q);
    // layer 2: agg(q1) -> mfma gemm+tanh -> q2   (q2 aliases q1; stream-ordered)
    k_aggq     <<<NN / 4, 256, 0, stream>>>(q, row_ptr, e_sn, dinv, aggf);
    k_gemm_q   <<<(NN + 63) / 64, 256, 0, stream>>>(aggf, w2hi, w2lo, b2, q);
    // layer 3: agg(q2) -> mfma gemm+tanh -> fused head (h3 never hits global)
    k_aggq     <<<NN / 4, 256, 0, stream>>>(q, row_ptr, e_sn, dinv, aggf);
    k_gemm_head<<<(NN + 63) / 64, 256, 0, stream>>>(aggf, w3hi, w3lo, b3, Wcc, bcc, outp);
}